// Round 10
// baseline (231.098 us; speedup 1.0000x reference)
//
#include <hip/hip_runtime.h>
#include <hip/hip_bf16.h>

typedef __bf16 bf16x8 __attribute__((ext_vector_type(8)));
typedef float  f32x4  __attribute__((ext_vector_type(4)));

#define NB   64      // batch
#define NPTS 10000   // nodes
#define KC0  128     // feature channels (GEMM K)
#define NC1  64      // kernel MLP out channels
#define NC2  256     // encoder out channels (GEMM M after operand swap)
#define GN   8       // n-tiles per block -> 1250 blocks

// ---------------------------------------------------------------------------
// Kernel 1: precompute, 9 blocks. (unchanged since round 5)
// ---------------------------------------------------------------------------
__global__ __launch_bounds__(256) void pe_precompute(
    const float* __restrict__ b1, const float* __restrict__ W2,
    const float* __restrict__ b2, const float* __restrict__ W3,
    const float* __restrict__ b3, const float* __restrict__ We,
    const float* __restrict__ be,
    __hip_bfloat16* __restrict__ WeT, float* __restrict__ cst)
{
    const int t  = threadIdx.x;
    const int bb = blockIdx.x;
    if (bb == 0) {
        __shared__ float sW2[8 * 16], sW3[16 * NC1], sb1[8], sb2[16], sb3[NC1], k0[NC1];
        if (t < 128) sW2[t] = W2[t];
        for (int i = t; i < 16 * NC1; i += 256) sW3[i] = W3[i];
        if (t < 8)  sb1[t] = b1[t];
        if (t < 16) sb2[t] = b2[t];
        if (t < NC1) sb3[t] = b3[t];
        __syncthreads();
        if (t < NC1) {
            float h1[8], h2[16];
            #pragma unroll
            for (int i = 0; i < 8; ++i) h1[i] = fmaxf(sb1[i], 0.f);  // x=0 -> relu(b1)
            #pragma unroll
            for (int j = 0; j < 16; ++j) {
                float s = sb2[j];
                #pragma unroll
                for (int i = 0; i < 8; ++i) s += h1[i] * sW2[i * 16 + j];
                h2[j] = fmaxf(s, 0.f);
            }
            float s = sb3[t];
            #pragma unroll
            for (int j = 0; j < 16; ++j) s += h2[j] * sW3[j * NC1 + t];
            k0[t] = s;
        }
        __syncthreads();
        float s = be[t];
        #pragma unroll 8
        for (int j = 0; j < NC1; ++j)
            s += k0[j] * We[(size_t)(KC0 + j) * NC2 + t];
        cst[t] = s;
    } else {
        __shared__ float sW[16][NC2];
        const int kbase = (bb - 1) * 16;
        #pragma unroll
        for (int kk = 0; kk < 16; ++kk)
            sW[kk][t] = We[(size_t)(kbase + kk) * NC2 + t];  // coalesced reads
        __syncthreads();
        bf16x8 lo, hi;
        #pragma unroll
        for (int kk = 0; kk < 8; ++kk) {
            lo[kk] = (__bf16)sW[kk][t];
            hi[kk] = (__bf16)sW[kk + 8][t];
        }
        __hip_bfloat16* wp = WeT + (size_t)t * KC0 + kbase;
        *reinterpret_cast<bf16x8*>(wp)     = lo;
        *reinterpret_cast<bf16x8*>(wp + 8) = hi;
    }
}

// ---------------------------------------------------------------------------
// Kernel 2: out[n,b,c] = feature[b,n,:] @ We[:128,c] + cst[c]
// Round-9 base (best, 213.2 us) + THIS ROUND'S single mechanism change:
// n-PHASE STAGGER. Row b of tile t holds feature[b][n0 + ((t+(b&7))&7)][:],
// so one tile's 64 reads (5.12-MB stride = 2^20*5 bytes: identical HBM
// channel phase for any pow2 channel map) now span 8 distinct 512-B phases.
// Over t=0..7 every (n,b) is covered exactly once. MFMA columns are
// independent dot-products -> mixed-n rows are valid; the store maps each
// row to its own n. Stores remain full-128-B-line via the wave-private
// granule-major LDS epilogue (each 8-lane group writes one aligned 128-B
// chunk at its row's n).
// Pipeline: depth-3 LA/LB/LC rotation (round-6 proven), 8 tiles, raw
// s_barrier + lgkmcnt(0) only. Input LDS involution gs = g ^ (row&7) both
// sides (rule #21). MFMA 16x16x32 (m89-verified), A = WeT, B = feature.
// ---------------------------------------------------------------------------
#define SYNC() do { \
    __builtin_amdgcn_sched_barrier(0); \
    asm volatile("s_waitcnt lgkmcnt(0)" ::: "memory"); \
    __builtin_amdgcn_s_barrier(); \
    __builtin_amdgcn_sched_barrier(0); \
} while (0)

__global__ __launch_bounds__(512, 4) void pe_gemm(
    const float* __restrict__ feat, const __hip_bfloat16* __restrict__ WeT,
    const float* __restrict__ cst, float* __restrict__ out)
{
    __shared__ __align__(16) __bf16 sbuf[2][64 * KC0];   // input dbuf: 2 x 16 KB
    __shared__ __align__(16) f32x4  sOut[8][8 * 32];     // out stage: 8 waves x 4 KB

    const int tid  = threadIdx.x;
    const int wave = tid >> 6;       // 0..7
    const int lane = tid & 63;
    const int lm   = lane & 15;
    const int lk   = lane >> 4;
    const int cbase = wave * 32;
    f32x4* const sOutW = sOut[wave]; // wave-private: in-wave lgkmcnt only

    // staging role: row sr (b), octant sq; k-segments [sq*8,+8) and [64+sq*8,+8)
    const int sr = tid >> 3;         // 0..63
    const int sq = tid & 7;          // 0..7
    const size_t n0 = (size_t)blockIdx.x * GN;
    const float* fbase = feat + ((size_t)sr * NPTS + n0) * KC0 + sq * 8;
    const int gsA = sq ^ (sr & 7);   // swizzled granule (segment A); B = +8
    __bf16* const wp0 = &sbuf[0][sr * KC0 + gsA * 8];   // segment A, buf 0
    const int BUFSTEP = 64 * KC0;                       // buf1 = wp0 + BUFSTEP
    const int sph = sr & 7;          // this staging row's n-phase

    // A fragments (WeT) + bias, resident for the whole block
    bf16x8 afrag[4][2];
    #pragma unroll
    for (int nn = 0; nn < 2; ++nn) {
        const __hip_bfloat16* wp = WeT + (size_t)(cbase + nn * 16 + lm) * KC0 + lk * 8;
        #pragma unroll
        for (int kk = 0; kk < 4; ++kk)
            afrag[kk][nn] = *reinterpret_cast<const bf16x8*>(wp + kk * 32);
    }
    f32x4 cv0 = *reinterpret_cast<const f32x4*>(cst + cbase + lk * 4);
    f32x4 cv1 = *reinterpret_cast<const f32x4*>(cst + cbase + 16 + lk * 4);

// staggered load: row sr of tile t comes from n = n0 + ((t + sph) & 7)
#define LOAD_TILE(L, t) do { \
    const float* fs_ = fbase + (size_t)(((t) + sph) & 7) * KC0; \
    L[0] = *reinterpret_cast<const f32x4*>(fs_); \
    L[1] = *reinterpret_cast<const f32x4*>(fs_ + 4); \
    L[2] = *reinterpret_cast<const f32x4*>(fs_ + 64); \
    L[3] = *reinterpret_cast<const f32x4*>(fs_ + 68); \
} while (0)

#define WRITE_TILE(L, buf) do { \
    bf16x8 hA_, hB_; \
    _Pragma("unroll") \
    for (int j = 0; j < 4; ++j) { \
        hA_[j] = (__bf16)L[0][j];  hA_[j + 4] = (__bf16)L[1][j]; \
        hB_[j] = (__bf16)L[2][j];  hB_[j + 4] = (__bf16)L[3][j]; \
    } \
    *reinterpret_cast<bf16x8*>(wp0 + (buf) * BUFSTEP)      = hA_; \
    *reinterpret_cast<bf16x8*>(wp0 + (buf) * BUFSTEP + 64) = hB_; \
} while (0)

// compute tile t; store row r to its own n = n0 + ((t + (r&7)) & 7)
#define COMPUTE_TILE(t, buf) do { \
    const __bf16* sb_ = &sbuf[buf][0]; \
    _Pragma("unroll") \
    for (int h_ = 0; h_ < 2; ++h_) { \
        _Pragma("unroll") \
        for (int m_ = 0; m_ < 2; ++m_) { \
            const int row_ = h_ * 32 + m_ * 16 + lm; \
            bf16x8 bfr_[4]; \
            _Pragma("unroll") \
            for (int kk = 0; kk < 4; ++kk) { \
                const int gs_ = (kk * 4 + lk) ^ (lm & 7); \
                bfr_[kk] = *reinterpret_cast<const bf16x8*>(sb_ + row_ * KC0 + gs_ * 8); \
            } \
            f32x4 a0_ = cv0, a1_ = cv1; \
            _Pragma("unroll") \
            for (int kk = 0; kk < 4; ++kk) { \
                a0_ = __builtin_amdgcn_mfma_f32_16x16x32_bf16(afrag[kk][0], bfr_[kk], a0_, 0, 0, 0); \
                a1_ = __builtin_amdgcn_mfma_f32_16x16x32_bf16(afrag[kk][1], bfr_[kk], a1_, 0, 0, 0); \
            } \
            sOutW[lk * 32 + m_ * 16 + lm]       = a0_; \
            sOutW[(lk + 4) * 32 + m_ * 16 + lm] = a1_; \
        } \
        asm volatile("s_waitcnt lgkmcnt(0)" ::: "memory"); /* in-wave only */ \
        _Pragma("unroll") \
        for (int p_ = 0; p_ < 4; ++p_) { \
            const int rr_  = p_ * 8 + (lane >> 3); \
            const int row_ = h_ * 32 + rr_; \
            const size_t nrow_ = n0 + (((t) + (row_ & 7)) & 7); \
            f32x4 v_ = sOutW[(lane & 7) * 32 + rr_]; \
            *reinterpret_cast<f32x4*>( \
                out + (nrow_ * NB + row_) * NC2 + cbase + (lane & 7) * 4) = v_; \
        } \
    } \
} while (0)

    f32x4 LA[4], LB[4], LC[4];
    // prologue: 12 loads in flight, stage tile 0, refill LA with tile 3
    LOAD_TILE(LA, 0);
    LOAD_TILE(LB, 1);
    LOAD_TILE(LC, 2);
    WRITE_TILE(LA, 0);          // waits only LA's 4 loads
    LOAD_TILE(LA, 3);

    SYNC();
    COMPUTE_TILE(0, 0);  WRITE_TILE(LB, 1);  LOAD_TILE(LB, 4);
    SYNC();
    COMPUTE_TILE(1, 1);  WRITE_TILE(LC, 0);  LOAD_TILE(LC, 5);
    SYNC();
    COMPUTE_TILE(2, 0);  WRITE_TILE(LA, 1);  LOAD_TILE(LA, 6);
    SYNC();
    COMPUTE_TILE(3, 1);  WRITE_TILE(LB, 0);  LOAD_TILE(LB, 7);
    SYNC();
    COMPUTE_TILE(4, 0);  WRITE_TILE(LC, 1);
    SYNC();
    COMPUTE_TILE(5, 1);  WRITE_TILE(LA, 0);
    SYNC();
    COMPUTE_TILE(6, 0);  WRITE_TILE(LB, 1);
    SYNC();
    COMPUTE_TILE(7, 1);

#undef LOAD_TILE
#undef WRITE_TILE
#undef COMPUTE_TILE
}

extern "C" void kernel_launch(void* const* d_in, const int* in_sizes, int n_in,
                              void* d_out, int out_size, void* d_ws, size_t ws_size,
                              hipStream_t stream) {
    const float* feat = (const float*)d_in[0];
    // d_in[1] = coordinates: unused (MLP input is identically zero)
    // d_in[2] = W1: unused (multiplies the zero vector)
    const float* b1 = (const float*)d_in[3];
    const float* W2 = (const float*)d_in[4];
    const float* b2 = (const float*)d_in[5];
    const float* W3 = (const float*)d_in[6];
    const float* b3 = (const float*)d_in[7];
    const float* We = (const float*)d_in[8];
    const float* be = (const float*)d_in[9];

    __hip_bfloat16* WeT = (__hip_bfloat16*)d_ws;                    // 256*128*2 = 64 KiB
    float*          cst = (float*)((char*)d_ws + NC2 * KC0 * 2);    // 256 floats, 16B-aligned

    pe_precompute<<<9, 256, 0, stream>>>(b1, W2, b2, W3, b3, We, be, WeT, cst);
    pe_gemm<<<NPTS / GN, 512, 0, stream>>>(feat, WeT, cst, (float*)d_out);
}

// Round 11
// 212.782 us; speedup vs baseline: 1.0861x; 1.0861x over previous
//
#include <hip/hip_runtime.h>
#include <hip/hip_bf16.h>

typedef __bf16 bf16x8 __attribute__((ext_vector_type(8)));
typedef float  f32x4  __attribute__((ext_vector_type(4)));

#define NB   64      // batch
#define NPTS 10000   // nodes
#define KC0  128     // feature channels (GEMM K)
#define NC1  64      // kernel MLP out channels
#define NC2  256     // encoder out channels (GEMM M after operand swap)
#define GN   4       // n-tiles per block -> 2500 blocks (round-9 best config)

// ---------------------------------------------------------------------------
// Kernel 1: precompute, 9 blocks.
//   block 0 : k0 = MLP(0); cst = k0 @ We[128:192,:] + be   [256] exact fp32
//   block b : WeT[c][k] = bf16(We[k][c]) for k-slice [(b-1)*16, (b-1)*16+16)
// ---------------------------------------------------------------------------
__global__ __launch_bounds__(256) void pe_precompute(
    const float* __restrict__ b1, const float* __restrict__ W2,
    const float* __restrict__ b2, const float* __restrict__ W3,
    const float* __restrict__ b3, const float* __restrict__ We,
    const float* __restrict__ be,
    __hip_bfloat16* __restrict__ WeT, float* __restrict__ cst)
{
    const int t  = threadIdx.x;
    const int bb = blockIdx.x;
    if (bb == 0) {
        __shared__ float sW2[8 * 16], sW3[16 * NC1], sb1[8], sb2[16], sb3[NC1], k0[NC1];
        if (t < 128) sW2[t] = W2[t];
        for (int i = t; i < 16 * NC1; i += 256) sW3[i] = W3[i];
        if (t < 8)  sb1[t] = b1[t];
        if (t < 16) sb2[t] = b2[t];
        if (t < NC1) sb3[t] = b3[t];
        __syncthreads();
        if (t < NC1) {
            float h1[8], h2[16];
            #pragma unroll
            for (int i = 0; i < 8; ++i) h1[i] = fmaxf(sb1[i], 0.f);  // x=0 -> relu(b1)
            #pragma unroll
            for (int j = 0; j < 16; ++j) {
                float s = sb2[j];
                #pragma unroll
                for (int i = 0; i < 8; ++i) s += h1[i] * sW2[i * 16 + j];
                h2[j] = fmaxf(s, 0.f);
            }
            float s = sb3[t];
            #pragma unroll
            for (int j = 0; j < 16; ++j) s += h2[j] * sW3[j * NC1 + t];
            k0[t] = s;
        }
        __syncthreads();
        float s = be[t];
        #pragma unroll 8
        for (int j = 0; j < NC1; ++j)
            s += k0[j] * We[(size_t)(KC0 + j) * NC2 + t];
        cst[t] = s;
    } else {
        __shared__ float sW[16][NC2];
        const int kbase = (bb - 1) * 16;
        #pragma unroll
        for (int kk = 0; kk < 16; ++kk)
            sW[kk][t] = We[(size_t)(kbase + kk) * NC2 + t];  // coalesced reads
        __syncthreads();
        bf16x8 lo, hi;
        #pragma unroll
        for (int kk = 0; kk < 8; ++kk) {
            lo[kk] = (__bf16)sW[kk][t];
            hi[kk] = (__bf16)sW[kk + 8][t];
        }
        __hip_bfloat16* wp = WeT + (size_t)t * KC0 + kbase;
        *reinterpret_cast<bf16x8*>(wp)     = lo;
        *reinterpret_cast<bf16x8*>(wp + 8) = hi;
    }
}

// ---------------------------------------------------------------------------
// Kernel 2: out[n,b,c] = feature[b,n,:] @ We[:128,c] + cst[c]
// MEASURED-BEST configuration (round 9, 213.2 us) — final.
// 512 thr / 8 waves, GN=4, depth-3 register prefetch LA/LB/LC, raw
// s_barrier + lgkmcnt(0) only (no vmcnt drain), input LDS involution
// swizzle gs = g ^ (row&7) both sides (rule #21), wave-private
// granule-major LDS store stage -> every global_store_dwordx4 writes
// full 128-B lines.
// MFMA 16x16x32 (m89-verified), A = WeT (c x k), B = feature (k x b):
//   A: lane l -> A[l&15][8*(l>>4)+j]        B: lane l -> B[8*(l>>4)+j][l&15]
//   D: lane l, reg r -> D[(l>>4)*4+r][l&15] (c = lk*4+r consecutive)
// Session ledger: pipeline structure -277us; NT stores -51 (reverted);
// depth/packing/page-locality/full-line-epilogue null; n-phase stagger
// -18 (reverted). Memory-bound at ~4.8 TB/s effective vs 6.6 TB/s
// fill-calibrated ceiling; remaining gap = compulsory 64-way 5.12-MB-stride
// read pattern of the [B,N,C] -> [N,B,C] transpose.
// ---------------------------------------------------------------------------
#define SYNC() do { \
    __builtin_amdgcn_sched_barrier(0); \
    asm volatile("s_waitcnt lgkmcnt(0)" ::: "memory"); \
    __builtin_amdgcn_s_barrier(); \
    __builtin_amdgcn_sched_barrier(0); \
} while (0)

__global__ __launch_bounds__(512, 4) void pe_gemm(
    const float* __restrict__ feat, const __hip_bfloat16* __restrict__ WeT,
    const float* __restrict__ cst, float* __restrict__ out)
{
    __shared__ __align__(16) __bf16 sbuf[2][64 * KC0];   // input dbuf: 2 x 16 KB
    __shared__ __align__(16) f32x4  sOut[8][8 * 32];     // out stage: 8 waves x 4 KB

    const int tid  = threadIdx.x;
    const int wave = tid >> 6;       // 0..7
    const int lane = tid & 63;
    const int lm   = lane & 15;
    const int lk   = lane >> 4;
    const int cbase = wave * 32;
    f32x4* const sOutW = sOut[wave]; // wave-private: no cross-wave sync needed

    // staging role: row sr (b), octant sq; k-segments [sq*8,+8) and [64+sq*8,+8)
    const int sr = tid >> 3;         // 0..63
    const int sq = tid & 7;          // 0..7
    const size_t n0 = (size_t)blockIdx.x * GN;
    const float* fstage = feat + ((size_t)sr * NPTS + n0) * KC0 + sq * 8;
    const int gsA = sq ^ (sr & 7);   // swizzled granule (segment A); B = +8
    __bf16* const wp0 = &sbuf[0][sr * KC0 + gsA * 8];   // segment A, buf 0
    const int BUFSTEP = 64 * KC0;                       // buf1 = wp0 + BUFSTEP

    // A fragments (WeT) + bias, resident for the whole block
    bf16x8 afrag[4][2];
    #pragma unroll
    for (int nn = 0; nn < 2; ++nn) {
        const __hip_bfloat16* wp = WeT + (size_t)(cbase + nn * 16 + lm) * KC0 + lk * 8;
        #pragma unroll
        for (int kk = 0; kk < 4; ++kk)
            afrag[kk][nn] = *reinterpret_cast<const bf16x8*>(wp + kk * 32);
    }
    f32x4 cv0 = *reinterpret_cast<const f32x4*>(cst + cbase + lk * 4);
    f32x4 cv1 = *reinterpret_cast<const f32x4*>(cst + cbase + 16 + lk * 4);

#define LOAD_TILE(L, t) do { \
    const float* fs_ = fstage + (size_t)(t) * KC0; \
    L[0] = *reinterpret_cast<const f32x4*>(fs_); \
    L[1] = *reinterpret_cast<const f32x4*>(fs_ + 4); \
    L[2] = *reinterpret_cast<const f32x4*>(fs_ + 64); \
    L[3] = *reinterpret_cast<const f32x4*>(fs_ + 68); \
} while (0)

#define WRITE_TILE(L, buf) do { \
    bf16x8 hA_, hB_; \
    _Pragma("unroll") \
    for (int j = 0; j < 4; ++j) { \
        hA_[j] = (__bf16)L[0][j];  hA_[j + 4] = (__bf16)L[1][j]; \
        hB_[j] = (__bf16)L[2][j];  hB_[j + 4] = (__bf16)L[3][j]; \
    } \
    *reinterpret_cast<bf16x8*>(wp0 + (buf) * BUFSTEP)      = hA_; \
    *reinterpret_cast<bf16x8*>(wp0 + (buf) * BUFSTEP + 64) = hB_; \
} while (0)

// Compute one n-tile from sbuf[buf]; epilogue stages each 32-row half in
// wave-private LDS, then streams 4 x (8 rows x 128 B full lines).
#define COMPUTE_TILE(t, buf) do { \
    const __bf16* sb_ = &sbuf[buf][0]; \
    float* on_ = out + ((n0 + (t)) * NB) * NC2 + cbase; \
    _Pragma("unroll") \
    for (int h_ = 0; h_ < 2; ++h_) { \
        _Pragma("unroll") \
        for (int m_ = 0; m_ < 2; ++m_) { \
            const int row_ = h_ * 32 + m_ * 16 + lm; \
            bf16x8 bfr_[4]; \
            _Pragma("unroll") \
            for (int kk = 0; kk < 4; ++kk) { \
                const int gs_ = (kk * 4 + lk) ^ (lm & 7); \
                bfr_[kk] = *reinterpret_cast<const bf16x8*>(sb_ + row_ * KC0 + gs_ * 8); \
            } \
            f32x4 a0_ = cv0, a1_ = cv1; \
            _Pragma("unroll") \
            for (int kk = 0; kk < 4; ++kk) { \
                a0_ = __builtin_amdgcn_mfma_f32_16x16x32_bf16(afrag[kk][0], bfr_[kk], a0_, 0, 0, 0); \
                a1_ = __builtin_amdgcn_mfma_f32_16x16x32_bf16(afrag[kk][1], bfr_[kk], a1_, 0, 0, 0); \
            } \
            /* stage: granule-major [g][row32], g=lk / lk+4, row=m_*16+lm */ \
            sOutW[lk * 32 + m_ * 16 + lm]       = a0_; \
            sOutW[(lk + 4) * 32 + m_ * 16 + lm] = a1_; \
        } \
        asm volatile("s_waitcnt lgkmcnt(0)" ::: "memory"); /* in-wave only */ \
        _Pragma("unroll") \
        for (int p_ = 0; p_ < 4; ++p_) { \
            const int rr_ = p_ * 8 + (lane >> 3); \
            f32x4 v_ = sOutW[(lane & 7) * 32 + rr_]; \
            *reinterpret_cast<f32x4*>( \
                on_ + (size_t)(h_ * 32 + rr_) * NC2 + (lane & 7) * 4) = v_; \
        } \
    } \
} while (0)

    f32x4 LA[4], LB[4], LC[4];
    // prologue: 12 loads in flight, then stage tile 0
    LOAD_TILE(LA, 0);
    LOAD_TILE(LB, 1);
    LOAD_TILE(LC, 2);
    WRITE_TILE(LA, 0);          // waits only LA's 4 loads

    LOAD_TILE(LA, 3);           // reuse set A for tile 3
    SYNC();
    COMPUTE_TILE(0, 0);
    WRITE_TILE(LB, 1);          // tile 1 -> buf1 (LB ~2 tiles in flight)

    SYNC();
    COMPUTE_TILE(1, 1);
    WRITE_TILE(LC, 0);          // tile 2 -> buf0 (readers of buf0 passed barrier)

    SYNC();
    COMPUTE_TILE(2, 0);
    WRITE_TILE(LA, 1);          // tile 3 -> buf1

    SYNC();
    COMPUTE_TILE(3, 1);

#undef LOAD_TILE
#undef WRITE_TILE
#undef COMPUTE_TILE
}

extern "C" void kernel_launch(void* const* d_in, const int* in_sizes, int n_in,
                              void* d_out, int out_size, void* d_ws, size_t ws_size,
                              hipStream_t stream) {
    const float* feat = (const float*)d_in[0];
    // d_in[1] = coordinates: unused (MLP input is identically zero)
    // d_in[2] = W1: unused (multiplies the zero vector)
    const float* b1 = (const float*)d_in[3];
    const float* W2 = (const float*)d_in[4];
    const float* b2 = (const float*)d_in[5];
    const float* W3 = (const float*)d_in[6];
    const float* b3 = (const float*)d_in[7];
    const float* We = (const float*)d_in[8];
    const float* be = (const float*)d_in[9];

    __hip_bfloat16* WeT = (__hip_bfloat16*)d_ws;                    // 256*128*2 = 64 KiB
    float*          cst = (float*)((char*)d_ws + NC2 * KC0 * 2);    // 256 floats, 16B-aligned

    pe_precompute<<<9, 256, 0, stream>>>(b1, W2, b2, W3, b3, We, be, WeT, cst);
    pe_gemm<<<NPTS / GN, 512, 0, stream>>>(feat, WeT, cst, (float*)d_out);
}